// Round 3
// baseline (684.020 us; speedup 1.0000x reference)
//
#include <hip/hip_runtime.h>

#define NUM_TEAMS 100000
#define EMBED     32
#define N_EDGES   2000000
#define BQ        524288
#define TARGET_DIM 3

// ---------------- CSR build ----------------

__global__ void hist_kernel(const int* __restrict__ dst, int* __restrict__ deg, int n) {
    int i = blockIdx.x * blockDim.x + threadIdx.x;
    if (i < n) atomicAdd(&deg[dst[i]], 1);
}

// ---- hierarchical exclusive scan over deg[n] ----
#define SCAN_CHUNK 2048

__global__ void __launch_bounds__(256) scan_partial(const int* __restrict__ deg,
                                                    int* __restrict__ bsum, int n) {
    __shared__ int wsum[4];
    int t = threadIdx.x;
    int base = blockIdx.x * SCAN_CHUNK + t * 8;
    int s = 0;
    #pragma unroll
    for (int k = 0; k < 8; ++k) { int idx = base + k; if (idx < n) s += deg[idx]; }
    #pragma unroll
    for (int off = 32; off > 0; off >>= 1) s += __shfl_down(s, off, 64);
    int lane = t & 63, wid = t >> 6;
    if (lane == 0) wsum[wid] = s;
    __syncthreads();
    if (t == 0) bsum[blockIdx.x] = wsum[0] + wsum[1] + wsum[2] + wsum[3];
}

__global__ void scan_bsums(int* __restrict__ bsum, int nb) {
    int t = threadIdx.x;
    int v = (t < nb) ? bsum[t] : 0;
    int incl = v;
    #pragma unroll
    for (int off = 1; off < 64; off <<= 1) {
        int u = __shfl_up(incl, off, 64);
        if (t >= off) incl += u;
    }
    if (t < nb) bsum[t] = incl - v;   // exclusive
}

__global__ void __launch_bounds__(256) scan_apply(const int* __restrict__ deg,
                                                  const int* __restrict__ bofs,
                                                  int* __restrict__ row_ptr,
                                                  int* __restrict__ cursor, int n) {
    __shared__ int wsum[4];
    int t = threadIdx.x;
    int base = blockIdx.x * SCAN_CHUNK + t * 8;
    int v[8];
    int s = 0;
    #pragma unroll
    for (int k = 0; k < 8; ++k) { int idx = base + k; v[k] = (idx < n) ? deg[idx] : 0; s += v[k]; }
    int lane = t & 63, wid = t >> 6;
    int incl = s;
    #pragma unroll
    for (int off = 1; off < 64; off <<= 1) {
        int u = __shfl_up(incl, off, 64);
        if (lane >= off) incl += u;
    }
    if (lane == 63) wsum[wid] = incl;
    __syncthreads();
    int wofs = 0;
    for (int w = 0; w < wid; ++w) wofs += wsum[w];
    int excl = incl - s + wofs + bofs[blockIdx.x];
    #pragma unroll
    for (int k = 0; k < 8; ++k) {
        int idx = base + k;
        if (idx < n) { row_ptr[idx] = excl; cursor[idx] = excl; }
        excl += v[k];
    }
    if (blockIdx.x == gridDim.x - 1 && t == 255) row_ptr[n] = excl;  // == N_EDGES
}

// Packed scatter: one 8B store per edge instead of two 4B stores to two arrays.
__global__ void fill_kernel(const int* __restrict__ src, const int* __restrict__ dst,
                            const float* __restrict__ ew, int* __restrict__ cursor,
                            int2* __restrict__ epack, int n) {
    int i = blockIdx.x * blockDim.x + threadIdx.x;
    if (i < n) {
        int d = dst[i];
        int p = atomicAdd(&cursor[d], 1);
        int2 v;
        v.x = src[i];
        v.y = __float_as_int(ew[i]);
        epack[p] = v;
    }
}

// ---------------- fused GraphConv layer ----------------
#define NODES_PER_BLOCK 8
__global__ void __launch_bounds__(256) conv_kernel(
        const float* __restrict__ x,
        const int* __restrict__ row_ptr,
        const int2* __restrict__ epack,
        const float* __restrict__ w_rel,   // [32][32] row-major
        const float* __restrict__ b_rel,   // [32]
        const float* __restrict__ w_root,  // [32][32]
        float* __restrict__ x_out, int num_nodes) {
    __shared__ float s_wrelT[32 * 32];   // transposed: [d][j]
    __shared__ float s_wrootT[32 * 32];
    __shared__ float s_b[32];
    __shared__ float s_agg[NODES_PER_BLOCK][32];
    __shared__ float s_x[NODES_PER_BLOCK][32];

    int t = threadIdx.x;
    for (int i = t; i < 1024; i += 256) {
        int j = i >> 5, d = i & 31;
        s_wrelT[d * 32 + j]  = w_rel[i];
        s_wrootT[d * 32 + j] = w_root[i];
    }
    if (t < 32) s_b[t] = b_rel[t];

    int local = t >> 5;        // node within block
    int lane  = t & 31;        // embedding dim
    int node  = blockIdx.x * NODES_PER_BLOCK + local;

    float acc = 0.f, xv = 0.f;
    if (node < num_nodes) {
        xv = x[node * EMBED + lane];
        int r0 = row_ptr[node], r1 = row_ptr[node + 1];
        for (int k = r0; k < r1; ++k) {
            int2  e = epack[k];              // broadcast within 32-lane group
            float w = __int_as_float(e.y);
            acc += w * x[e.x * EMBED + lane];
        }
    }
    s_agg[local][lane] = acc;
    s_x[local][lane]   = xv;
    __syncthreads();

    if (node < num_nodes) {
        float o = s_b[lane];
        #pragma unroll
        for (int d = 0; d < 32; ++d) {
            o += s_wrelT[d * 32 + lane] * s_agg[local][d]
               + s_wrootT[d * 32 + lane] * s_x[local][d];
        }
        o = (o >= 0.f) ? o : 0.01f * o;
        x_out[node * EMBED + lane] = o;
    }
}

// ---------------- final pair MLP + log_softmax ----------------
__global__ void __launch_bounds__(256) mlp_kernel(
        const float* __restrict__ x,
        const int* __restrict__ home, const int* __restrict__ away,
        const float* __restrict__ w0, const float* __restrict__ b0,
        const float* __restrict__ w1, const float* __restrict__ b1,
        const float* __restrict__ w2, const float* __restrict__ b2,
        const float* __restrict__ w3, const float* __restrict__ b3,
        const float* __restrict__ w4, const float* __restrict__ b4,
        float* __restrict__ out, int n) {
    __shared__ float s_w0[512], s_w1[64], s_w2[64], s_w3[64], s_w4[24];
    __shared__ float s_b0[8], s_b1[8], s_b2[8], s_b3[8], s_b4[3];
    int t = threadIdx.x;
    for (int i = t; i < 512; i += 256) s_w0[i] = w0[i];
    if (t < 64) { s_w1[t] = w1[t]; s_w2[t] = w2[t]; s_w3[t] = w3[t]; }
    if (t < 24) s_w4[t] = w4[t];
    if (t < 8)  { s_b0[t] = b0[t]; s_b1[t] = b1[t]; s_b2[t] = b2[t]; s_b3[t] = b3[t]; }
    if (t < 3)  s_b4[t] = b4[t];
    __syncthreads();

    int i = blockIdx.x * 256 + t;
    if (i >= n) return;

    float hv[64];
    {
        const float4* ph = (const float4*)(x + (size_t)home[i] * EMBED);
        const float4* pa = (const float4*)(x + (size_t)away[i] * EMBED);
        #pragma unroll
        for (int q = 0; q < 8; ++q) {
            float4 v = ph[q];
            hv[4*q+0] = v.x; hv[4*q+1] = v.y; hv[4*q+2] = v.z; hv[4*q+3] = v.w;
        }
        #pragma unroll
        for (int q = 0; q < 8; ++q) {
            float4 v = pa[q];
            hv[32+4*q+0] = v.x; hv[32+4*q+1] = v.y; hv[32+4*q+2] = v.z; hv[32+4*q+3] = v.w;
        }
    }

    float h1[8];
    #pragma unroll
    for (int j = 0; j < 8; ++j) {
        float o = s_b0[j];
        #pragma unroll
        for (int d = 0; d < 64; ++d) o += s_w0[j * 64 + d] * hv[d];
        h1[j] = (o >= 0.f) ? o : 0.01f * o;
    }
    float h2[8];
    #pragma unroll
    for (int j = 0; j < 8; ++j) {
        float o = s_b1[j];
        #pragma unroll
        for (int d = 0; d < 8; ++d) o += s_w1[j * 8 + d] * h1[d];
        h2[j] = (o >= 0.f) ? o : 0.01f * o;
    }
    float h3[8];
    #pragma unroll
    for (int j = 0; j < 8; ++j) {
        float o = s_b2[j];
        #pragma unroll
        for (int d = 0; d < 8; ++d) o += s_w2[j * 8 + d] * h2[d];
        h3[j] = (o >= 0.f) ? o : 0.01f * o;
    }
    float h4[8];
    #pragma unroll
    for (int j = 0; j < 8; ++j) {
        float o = s_b3[j];
        #pragma unroll
        for (int d = 0; d < 8; ++d) o += s_w3[j * 8 + d] * h3[d];
        h4[j] = (o >= 0.f) ? o : 0.01f * o;
    }
    float f[3];
    #pragma unroll
    for (int j = 0; j < 3; ++j) {
        float o = s_b4[j];
        #pragma unroll
        for (int d = 0; d < 8; ++d) o += s_w4[j * 8 + d] * h4[d];
        f[j] = (o >= 0.f) ? o : 0.01f * o;
    }
    float m  = fmaxf(f[0], fmaxf(f[1], f[2]));
    float s  = expf(f[0] - m) + expf(f[1] - m) + expf(f[2] - m);
    float ls = logf(s);
    out[3 * i + 0] = f[0] - m - ls;
    out[3 * i + 1] = f[1] - m - ls;
    out[3 * i + 2] = f[2] - m - ls;
}

// ---------------- launch ----------------

extern "C" void kernel_launch(void* const* d_in, const int* in_sizes, int n_in,
                              void* d_out, int out_size, void* d_ws, size_t ws_size,
                              hipStream_t stream) {
    const int*   edge_index = (const int*)d_in[0];
    const int*   src   = edge_index;
    const int*   dst   = edge_index + N_EDGES;
    const float* ew    = (const float*)d_in[1];
    const int*   home  = (const int*)d_in[2];
    const int*   away  = (const int*)d_in[3];
    const float* embed = (const float*)d_in[4];
    const float* w_rel  = (const float*)d_in[5];
    const float* b_rel  = (const float*)d_in[6];
    const float* w_root = (const float*)d_in[7];
    const float* w0 = (const float*)d_in[8];  const float* b0 = (const float*)d_in[9];
    const float* w1 = (const float*)d_in[10]; const float* b1 = (const float*)d_in[11];
    const float* w2 = (const float*)d_in[12]; const float* b2 = (const float*)d_in[13];
    const float* w3 = (const float*)d_in[14]; const float* b3 = (const float*)d_in[15];
    const float* w4 = (const float*)d_in[16]; const float* b4 = (const float*)d_in[17];
    float* out = (float*)d_out;

    char* ws = (char*)d_ws;
    size_t off = 0;
    auto carve = [&](size_t bytes) -> void* {
        void* p = ws + off;
        off += (bytes + 15) & ~(size_t)15;
        return p;
    };
    int*   row_ptr = (int*)  carve((NUM_TEAMS + 1) * sizeof(int));
    int*   deg     = (int*)  carve(NUM_TEAMS * sizeof(int));
    int*   cursor  = (int*)  carve(NUM_TEAMS * sizeof(int));
    int*   bsum    = (int*)  carve(64 * sizeof(int));
    int2*  epack   = (int2*) carve((size_t)N_EDGES * sizeof(int2));
    float* x1      = (float*)carve((size_t)NUM_TEAMS * EMBED * sizeof(float));
    float* x2      = (float*)carve((size_t)NUM_TEAMS * EMBED * sizeof(float));
    (void)ws_size; (void)in_sizes; (void)n_in; (void)out_size;

    const int edge_blocks = (N_EDGES + 255) / 256;
    const int conv_blocks = (NUM_TEAMS + NODES_PER_BLOCK - 1) / NODES_PER_BLOCK;
    const int mlp_blocks  = (BQ + 255) / 256;
    const int scan_blocks = (NUM_TEAMS + SCAN_CHUNK - 1) / SCAN_CHUNK;  // 49

    hipMemsetAsync(deg, 0, NUM_TEAMS * sizeof(int), stream);
    hist_kernel<<<edge_blocks, 256, 0, stream>>>(dst, deg, N_EDGES);
    scan_partial<<<scan_blocks, 256, 0, stream>>>(deg, bsum, NUM_TEAMS);
    scan_bsums<<<1, 64, 0, stream>>>(bsum, scan_blocks);
    scan_apply<<<scan_blocks, 256, 0, stream>>>(deg, bsum, row_ptr, cursor, NUM_TEAMS);
    fill_kernel<<<edge_blocks, 256, 0, stream>>>(src, dst, ew, cursor, epack, N_EDGES);

    conv_kernel<<<conv_blocks, 256, 0, stream>>>(embed, row_ptr, epack,
        w_rel + 0 * 1024, b_rel + 0 * 32, w_root + 0 * 1024, x1, NUM_TEAMS);
    conv_kernel<<<conv_blocks, 256, 0, stream>>>(x1, row_ptr, epack,
        w_rel + 1 * 1024, b_rel + 1 * 32, w_root + 1 * 1024, x2, NUM_TEAMS);
    conv_kernel<<<conv_blocks, 256, 0, stream>>>(x2, row_ptr, epack,
        w_rel + 2 * 1024, b_rel + 2 * 32, w_root + 2 * 1024, x1, NUM_TEAMS);

    mlp_kernel<<<mlp_blocks, 256, 0, stream>>>(x1, home, away,
        w0, b0, w1, b1, w2, b2, w3, b3, w4, b4, out, BQ);
}

// Round 4
// 500.691 us; speedup vs baseline: 1.3662x; 1.3662x over previous
//
#include <hip/hip_runtime.h>

#define NUM_TEAMS 100000
#define EMBED     32
#define N_EDGES   2000000
#define BQ        524288
#define TARGET_DIM 3

// ---- bucket partition parameters ----
#define BSH    9                       // bucket = dst >> 9
#define BSPAN  512                     // dst values per bucket
#define NBUCK  ((NUM_TEAMS + BSPAN - 1) / BSPAN)   // 196
#define TILE   8192                    // edges per partition block
#define P2_BLOCKS ((N_EDGES + TILE - 1) / TILE)    // 245

// ---------------- P1: bucket histogram ----------------
__global__ void __launch_bounds__(256) bhist_kernel(const int* __restrict__ dst,
                                                    int* __restrict__ bhist, int n) {
    __shared__ int cnt[NBUCK];
    int t = threadIdx.x;
    for (int i = t; i < NBUCK; i += 256) cnt[i] = 0;
    __syncthreads();
    int base = blockIdx.x * TILE;
    for (int j = 0; j < TILE; j += 256) {
        int i = base + j + t;
        if (i < n) atomicAdd(&cnt[dst[i] >> BSH], 1);
    }
    __syncthreads();
    for (int i = t; i < NBUCK; i += 256) if (cnt[i]) atomicAdd(&bhist[i], cnt[i]);
}

// ---------------- P1b: scan bucket counts (1 block) ----------------
__global__ void __launch_bounds__(256) bscan_kernel(const int* __restrict__ bhist,
                                                    int* __restrict__ bbase,
                                                    int* __restrict__ bcursor,
                                                    int* __restrict__ row_ptr) {
    __shared__ int wsum[4];
    int t = threadIdx.x;
    int v = (t < NBUCK) ? bhist[t] : 0;
    int lane = t & 63, wid = t >> 6;
    int incl = v;
    #pragma unroll
    for (int off = 1; off < 64; off <<= 1) {
        int u = __shfl_up(incl, off, 64);
        if (lane >= off) incl += u;
    }
    if (lane == 63) wsum[wid] = incl;
    __syncthreads();
    int wofs = 0;
    for (int w = 0; w < wid; ++w) wofs += wsum[w];
    int excl = incl - v + wofs;
    if (t < NBUCK) { bbase[t] = excl; bcursor[t] = excl; }
    if (t == 0) { bbase[NBUCK] = N_EDGES; row_ptr[NUM_TEAMS] = N_EDGES; }
}

// ---------------- P2: chunked partition into bucket regions ----------------
// rec.x = src | (dst_local << 17)   (src < 2^17, dst_local < 512)
__global__ void __launch_bounds__(256) partition_kernel(
        const int* __restrict__ src, const int* __restrict__ dst,
        const float* __restrict__ ew,
        int* __restrict__ bcursor, int2* __restrict__ recs, int n) {
    __shared__ int cnt[NBUCK];
    __shared__ int lbase[NBUCK];
    int t = threadIdx.x;
    for (int i = t; i < NBUCK; i += 256) cnt[i] = 0;
    __syncthreads();
    int base = blockIdx.x * TILE;
    for (int j = 0; j < TILE; j += 256) {
        int i = base + j + t;
        if (i < n) atomicAdd(&cnt[dst[i] >> BSH], 1);
    }
    __syncthreads();
    for (int b = t; b < NBUCK; b += 256) {
        int c = cnt[b];
        lbase[b] = c ? atomicAdd(&bcursor[b], c) : 0;
        cnt[b] = 0;                    // reuse as local cursor
    }
    __syncthreads();
    for (int j = 0; j < TILE; j += 256) {
        int i = base + j + t;
        if (i < n) {
            int d = dst[i];
            int b = d >> BSH;
            int r = atomicAdd(&cnt[b], 1);
            int2 rec;
            rec.x = src[i] | ((d & (BSPAN - 1)) << 17);
            rec.y = __float_as_int(ew[i]);
            recs[lbase[b] + r] = rec;
        }
    }
}

// ---------------- P3: per-bucket CSR finalize ----------------
__global__ void __launch_bounds__(256) finalize_kernel(
        const int2* __restrict__ recs, const int* __restrict__ bbase,
        int* __restrict__ row_ptr, int2* __restrict__ epack) {
    __shared__ int cnt[BSPAN];
    __shared__ int excl[BSPAN];
    int b = blockIdx.x;
    int t = threadIdx.x;
    int rbase = bbase[b], rend = bbase[b + 1];
    for (int i = t; i < BSPAN; i += 256) cnt[i] = 0;
    __syncthreads();
    for (int k = rbase + t; k < rend; k += 256)
        atomicAdd(&cnt[recs[k].x >> 17], 1);
    __syncthreads();
    // exclusive scan of 512 counts by wave 0 (lane l owns elements l*8..l*8+7)
    if (t < 64) {
        int c[8]; int s = 0;
        #pragma unroll
        for (int k = 0; k < 8; ++k) { c[k] = cnt[t * 8 + k]; s += c[k]; }
        int incl = s;
        #pragma unroll
        for (int off = 1; off < 64; off <<= 1) {
            int u = __shfl_up(incl, off, 64);
            if (t >= off) incl += u;
        }
        int e = incl - s;
        #pragma unroll
        for (int k = 0; k < 8; ++k) { excl[t * 8 + k] = e; e += c[k]; }
    }
    __syncthreads();
    for (int i = t; i < BSPAN; i += 256) {
        int node = b * BSPAN + i;
        if (node < NUM_TEAMS) row_ptr[node] = rbase + excl[i];
        cnt[i] = excl[i];              // reuse as cursor
    }
    __syncthreads();
    for (int k = rbase + t; k < rend; k += 256) {
        int2 rec = recs[k];
        int dloc = rec.x >> 17;
        int r = atomicAdd(&cnt[dloc], 1);
        int2 e; e.x = rec.x & 0x1FFFF; e.y = rec.y;
        epack[rbase + r] = e;          // scatter within ~80KB window (L2-local)
    }
}

// ---------------- fused GraphConv layer ----------------
#define NODES_PER_BLOCK 8
__global__ void __launch_bounds__(256) conv_kernel(
        const float* __restrict__ x,
        const int* __restrict__ row_ptr,
        const int2* __restrict__ epack,
        const float* __restrict__ w_rel,   // [32][32] row-major
        const float* __restrict__ b_rel,   // [32]
        const float* __restrict__ w_root,  // [32][32]
        float* __restrict__ x_out, int num_nodes) {
    __shared__ float s_wrelT[32 * 32];   // transposed: [d][j]
    __shared__ float s_wrootT[32 * 32];
    __shared__ float s_b[32];
    __shared__ float s_agg[NODES_PER_BLOCK][32];
    __shared__ float s_x[NODES_PER_BLOCK][32];

    int t = threadIdx.x;
    for (int i = t; i < 1024; i += 256) {
        int j = i >> 5, d = i & 31;
        s_wrelT[d * 32 + j]  = w_rel[i];
        s_wrootT[d * 32 + j] = w_root[i];
    }
    if (t < 32) s_b[t] = b_rel[t];

    int local = t >> 5;        // node within block
    int lane  = t & 31;        // embedding dim
    int node  = blockIdx.x * NODES_PER_BLOCK + local;

    float acc = 0.f, xv = 0.f;
    if (node < num_nodes) {
        xv = x[node * EMBED + lane];
        int r0 = row_ptr[node], r1 = row_ptr[node + 1];
        for (int k = r0; k < r1; ++k) {
            int2  e = epack[k];              // broadcast within 32-lane group
            float w = __int_as_float(e.y);
            acc += w * x[e.x * EMBED + lane];
        }
    }
    s_agg[local][lane] = acc;
    s_x[local][lane]   = xv;
    __syncthreads();

    if (node < num_nodes) {
        float o = s_b[lane];
        #pragma unroll
        for (int d = 0; d < 32; ++d) {
            o += s_wrelT[d * 32 + lane] * s_agg[local][d]
               + s_wrootT[d * 32 + lane] * s_x[local][d];
        }
        o = (o >= 0.f) ? o : 0.01f * o;
        x_out[node * EMBED + lane] = o;
    }
}

// ---------------- final pair MLP + log_softmax ----------------
__global__ void __launch_bounds__(256) mlp_kernel(
        const float* __restrict__ x,
        const int* __restrict__ home, const int* __restrict__ away,
        const float* __restrict__ w0, const float* __restrict__ b0,
        const float* __restrict__ w1, const float* __restrict__ b1,
        const float* __restrict__ w2, const float* __restrict__ b2,
        const float* __restrict__ w3, const float* __restrict__ b3,
        const float* __restrict__ w4, const float* __restrict__ b4,
        float* __restrict__ out, int n) {
    __shared__ float s_w0[512], s_w1[64], s_w2[64], s_w3[64], s_w4[24];
    __shared__ float s_b0[8], s_b1[8], s_b2[8], s_b3[8], s_b4[3];
    int t = threadIdx.x;
    for (int i = t; i < 512; i += 256) s_w0[i] = w0[i];
    if (t < 64) { s_w1[t] = w1[t]; s_w2[t] = w2[t]; s_w3[t] = w3[t]; }
    if (t < 24) s_w4[t] = w4[t];
    if (t < 8)  { s_b0[t] = b0[t]; s_b1[t] = b1[t]; s_b2[t] = b2[t]; s_b3[t] = b3[t]; }
    if (t < 3)  s_b4[t] = b4[t];
    __syncthreads();

    int i = blockIdx.x * 256 + t;
    if (i >= n) return;

    float hv[64];
    {
        const float4* ph = (const float4*)(x + (size_t)home[i] * EMBED);
        const float4* pa = (const float4*)(x + (size_t)away[i] * EMBED);
        #pragma unroll
        for (int q = 0; q < 8; ++q) {
            float4 v = ph[q];
            hv[4*q+0] = v.x; hv[4*q+1] = v.y; hv[4*q+2] = v.z; hv[4*q+3] = v.w;
        }
        #pragma unroll
        for (int q = 0; q < 8; ++q) {
            float4 v = pa[q];
            hv[32+4*q+0] = v.x; hv[32+4*q+1] = v.y; hv[32+4*q+2] = v.z; hv[32+4*q+3] = v.w;
        }
    }

    float h1[8];
    #pragma unroll
    for (int j = 0; j < 8; ++j) {
        float o = s_b0[j];
        #pragma unroll
        for (int d = 0; d < 64; ++d) o += s_w0[j * 64 + d] * hv[d];
        h1[j] = (o >= 0.f) ? o : 0.01f * o;
    }
    float h2[8];
    #pragma unroll
    for (int j = 0; j < 8; ++j) {
        float o = s_b1[j];
        #pragma unroll
        for (int d = 0; d < 8; ++d) o += s_w1[j * 8 + d] * h1[d];
        h2[j] = (o >= 0.f) ? o : 0.01f * o;
    }
    float h3[8];
    #pragma unroll
    for (int j = 0; j < 8; ++j) {
        float o = s_b2[j];
        #pragma unroll
        for (int d = 0; d < 8; ++d) o += s_w2[j * 8 + d] * h2[d];
        h3[j] = (o >= 0.f) ? o : 0.01f * o;
    }
    float h4[8];
    #pragma unroll
    for (int j = 0; j < 8; ++j) {
        float o = s_b3[j];
        #pragma unroll
        for (int d = 0; d < 8; ++d) o += s_w3[j * 8 + d] * h3[d];
        h4[j] = (o >= 0.f) ? o : 0.01f * o;
    }
    float f[3];
    #pragma unroll
    for (int j = 0; j < 3; ++j) {
        float o = s_b4[j];
        #pragma unroll
        for (int d = 0; d < 8; ++d) o += s_w4[j * 8 + d] * h4[d];
        f[j] = (o >= 0.f) ? o : 0.01f * o;
    }
    float m  = fmaxf(f[0], fmaxf(f[1], f[2]));
    float s  = expf(f[0] - m) + expf(f[1] - m) + expf(f[2] - m);
    float ls = logf(s);
    out[3 * i + 0] = f[0] - m - ls;
    out[3 * i + 1] = f[1] - m - ls;
    out[3 * i + 2] = f[2] - m - ls;
}

// ---------------- launch ----------------

extern "C" void kernel_launch(void* const* d_in, const int* in_sizes, int n_in,
                              void* d_out, int out_size, void* d_ws, size_t ws_size,
                              hipStream_t stream) {
    const int*   edge_index = (const int*)d_in[0];
    const int*   src   = edge_index;
    const int*   dst   = edge_index + N_EDGES;
    const float* ew    = (const float*)d_in[1];
    const int*   home  = (const int*)d_in[2];
    const int*   away  = (const int*)d_in[3];
    const float* embed = (const float*)d_in[4];
    const float* w_rel  = (const float*)d_in[5];
    const float* b_rel  = (const float*)d_in[6];
    const float* w_root = (const float*)d_in[7];
    const float* w0 = (const float*)d_in[8];  const float* b0 = (const float*)d_in[9];
    const float* w1 = (const float*)d_in[10]; const float* b1 = (const float*)d_in[11];
    const float* w2 = (const float*)d_in[12]; const float* b2 = (const float*)d_in[13];
    const float* w3 = (const float*)d_in[14]; const float* b3 = (const float*)d_in[15];
    const float* w4 = (const float*)d_in[16]; const float* b4 = (const float*)d_in[17];
    float* out = (float*)d_out;

    char* ws = (char*)d_ws;
    size_t off = 0;
    auto carve = [&](size_t bytes) -> void* {
        void* p = ws + off;
        off += (bytes + 255) & ~(size_t)255;
        return p;
    };
    int*   row_ptr = (int*)  carve((NUM_TEAMS + 1) * sizeof(int));
    int*   bhist   = (int*)  carve(NBUCK * sizeof(int));
    int*   bbase   = (int*)  carve((NBUCK + 1) * sizeof(int));
    int*   bcursor = (int*)  carve(NBUCK * sizeof(int));
    int2*  recs    = (int2*) carve((size_t)N_EDGES * sizeof(int2));   // dead after P3
    int2*  epack   = (int2*) carve((size_t)N_EDGES * sizeof(int2));
    float* x1      = (float*)recs;   // alias: conv outputs reuse recs region (12.8MB <= 16MB)
    float* x2      = (float*)carve((size_t)NUM_TEAMS * EMBED * sizeof(float));
    (void)ws_size; (void)in_sizes; (void)n_in; (void)out_size;

    const int conv_blocks = (NUM_TEAMS + NODES_PER_BLOCK - 1) / NODES_PER_BLOCK;
    const int mlp_blocks  = (BQ + 255) / 256;

    hipMemsetAsync(bhist, 0, NBUCK * sizeof(int), stream);
    bhist_kernel<<<P2_BLOCKS, 256, 0, stream>>>(dst, bhist, N_EDGES);
    bscan_kernel<<<1, 256, 0, stream>>>(bhist, bbase, bcursor, row_ptr);
    partition_kernel<<<P2_BLOCKS, 256, 0, stream>>>(src, dst, ew, bcursor, recs, N_EDGES);
    finalize_kernel<<<NBUCK, 256, 0, stream>>>(recs, bbase, row_ptr, epack);

    conv_kernel<<<conv_blocks, 256, 0, stream>>>(embed, row_ptr, epack,
        w_rel + 0 * 1024, b_rel + 0 * 32, w_root + 0 * 1024, x1, NUM_TEAMS);
    conv_kernel<<<conv_blocks, 256, 0, stream>>>(x1, row_ptr, epack,
        w_rel + 1 * 1024, b_rel + 1 * 32, w_root + 1 * 1024, x2, NUM_TEAMS);
    conv_kernel<<<conv_blocks, 256, 0, stream>>>(x2, row_ptr, epack,
        w_rel + 2 * 1024, b_rel + 2 * 32, w_root + 2 * 1024, x1, NUM_TEAMS);

    mlp_kernel<<<mlp_blocks, 256, 0, stream>>>(x1, home, away,
        w0, b0, w1, b1, w2, b2, w3, b3, w4, b4, out, BQ);
}

// Round 5
// 407.047 us; speedup vs baseline: 1.6804x; 1.2301x over previous
//
#include <hip/hip_runtime.h>

#define NUM_TEAMS 100000
#define EMBED     32
#define N_EDGES   2000000
#define BQ        524288
#define TARGET_DIM 3

// ---- bucket partition parameters ----
#define BSH    9                       // bucket = dst >> 9
#define BSPAN  512                     // dst values per bucket
#define NBUCK  ((NUM_TEAMS + BSPAN - 1) / BSPAN)   // 196
#define TILE   8192                    // edges per partition block
#define P2_BLOCKS ((N_EDGES + TILE - 1) / TILE)    // 245

// ---------------- P1: bucket histogram ----------------
__global__ void __launch_bounds__(256) bhist_kernel(const int* __restrict__ dst,
                                                    int* __restrict__ bhist, int n) {
    __shared__ int cnt[NBUCK];
    int t = threadIdx.x;
    for (int i = t; i < NBUCK; i += 256) cnt[i] = 0;
    __syncthreads();
    int base = blockIdx.x * TILE;
    for (int j = 0; j < TILE; j += 256) {
        int i = base + j + t;
        if (i < n) atomicAdd(&cnt[dst[i] >> BSH], 1);
    }
    __syncthreads();
    for (int i = t; i < NBUCK; i += 256) if (cnt[i]) atomicAdd(&bhist[i], cnt[i]);
}

// ---------------- P1b: scan bucket counts (1 block) ----------------
__global__ void __launch_bounds__(256) bscan_kernel(const int* __restrict__ bhist,
                                                    int* __restrict__ bbase,
                                                    int* __restrict__ bcursor,
                                                    int* __restrict__ row_ptr) {
    __shared__ int wsum[4];
    int t = threadIdx.x;
    int v = (t < NBUCK) ? bhist[t] : 0;
    int lane = t & 63, wid = t >> 6;
    int incl = v;
    #pragma unroll
    for (int off = 1; off < 64; off <<= 1) {
        int u = __shfl_up(incl, off, 64);
        if (lane >= off) incl += u;
    }
    if (lane == 63) wsum[wid] = incl;
    __syncthreads();
    int wofs = 0;
    for (int w = 0; w < wid; ++w) wofs += wsum[w];
    int excl = incl - v + wofs;
    if (t < NBUCK) { bbase[t] = excl; bcursor[t] = excl; }
    if (t == 0) { bbase[NBUCK] = N_EDGES; row_ptr[NUM_TEAMS] = N_EDGES; }
}

// ---------------- P2: chunked partition into bucket regions ----------------
// rec.x = src | (dst_local << 17)   (src < 2^17, dst_local < 512)
__global__ void __launch_bounds__(256) partition_kernel(
        const int* __restrict__ src, const int* __restrict__ dst,
        const float* __restrict__ ew,
        int* __restrict__ bcursor, int2* __restrict__ recs, int n) {
    __shared__ int cnt[NBUCK];
    __shared__ int lbase[NBUCK];
    int t = threadIdx.x;
    for (int i = t; i < NBUCK; i += 256) cnt[i] = 0;
    __syncthreads();
    int base = blockIdx.x * TILE;
    for (int j = 0; j < TILE; j += 256) {
        int i = base + j + t;
        if (i < n) atomicAdd(&cnt[dst[i] >> BSH], 1);
    }
    __syncthreads();
    for (int b = t; b < NBUCK; b += 256) {
        int c = cnt[b];
        lbase[b] = c ? atomicAdd(&bcursor[b], c) : 0;
        cnt[b] = 0;                    // reuse as local cursor
    }
    __syncthreads();
    for (int j = 0; j < TILE; j += 256) {
        int i = base + j + t;
        if (i < n) {
            int d = dst[i];
            int b = d >> BSH;
            int r = atomicAdd(&cnt[b], 1);
            int2 rec;
            rec.x = src[i] | ((d & (BSPAN - 1)) << 17);
            rec.y = __float_as_int(ew[i]);
            recs[lbase[b] + r] = rec;
        }
    }
}

// ---------------- P3: per-bucket CSR finalize ----------------
__global__ void __launch_bounds__(256) finalize_kernel(
        const int2* __restrict__ recs, const int* __restrict__ bbase,
        int* __restrict__ row_ptr, int2* __restrict__ epack) {
    __shared__ int cnt[BSPAN];
    __shared__ int excl[BSPAN];
    int b = blockIdx.x;
    int t = threadIdx.x;
    int rbase = bbase[b], rend = bbase[b + 1];
    for (int i = t; i < BSPAN; i += 256) cnt[i] = 0;
    __syncthreads();
    for (int k = rbase + t; k < rend; k += 256)
        atomicAdd(&cnt[recs[k].x >> 17], 1);
    __syncthreads();
    // exclusive scan of 512 counts by wave 0 (lane l owns elements l*8..l*8+7)
    if (t < 64) {
        int c[8]; int s = 0;
        #pragma unroll
        for (int k = 0; k < 8; ++k) { c[k] = cnt[t * 8 + k]; s += c[k]; }
        int incl = s;
        #pragma unroll
        for (int off = 1; off < 64; off <<= 1) {
            int u = __shfl_up(incl, off, 64);
            if (t >= off) incl += u;
        }
        int e = incl - s;
        #pragma unroll
        for (int k = 0; k < 8; ++k) { excl[t * 8 + k] = e; e += c[k]; }
    }
    __syncthreads();
    for (int i = t; i < BSPAN; i += 256) {
        int node = b * BSPAN + i;
        if (node < NUM_TEAMS) row_ptr[node] = rbase + excl[i];
        cnt[i] = excl[i];              // reuse as cursor
    }
    __syncthreads();
    for (int k = rbase + t; k < rend; k += 256) {
        int2 rec = recs[k];
        int dloc = rec.x >> 17;
        int r = atomicAdd(&cnt[dloc], 1);
        int2 e; e.x = rec.x & 0x1FFFF; e.y = rec.y;
        epack[rbase + r] = e;          // scatter within ~80KB window (L2-local)
    }
}

// ---------------- fused GraphConv layer ----------------
// block = 256 threads = 8 nodes x 32 lanes. lane = embedding dim.
// Gather loop: predicated unroll-by-8 -> 8 gathers in flight per iteration.
// LDS arrays padded to stride 33 (kills 32-way staging-write conflict).
#define NODES_PER_BLOCK 8
__global__ void __launch_bounds__(256) conv_kernel(
        const float* __restrict__ x,
        const int* __restrict__ row_ptr,
        const int2* __restrict__ epack,
        const float* __restrict__ w_rel,   // [32][32] row-major
        const float* __restrict__ b_rel,   // [32]
        const float* __restrict__ w_root,  // [32][32]
        float* __restrict__ x_out, int num_nodes) {
    __shared__ float s_wrelT[32 * 33];   // transposed+padded: [d][j] at d*33+j
    __shared__ float s_wrootT[32 * 33];
    __shared__ float s_b[32];
    __shared__ float s_agg[NODES_PER_BLOCK * 33];
    __shared__ float s_x[NODES_PER_BLOCK * 33];

    int t = threadIdx.x;
    for (int i = t; i < 1024; i += 256) {
        int j = i >> 5, d = i & 31;
        s_wrelT[d * 33 + j]  = w_rel[i];
        s_wrootT[d * 33 + j] = w_root[i];
    }
    if (t < 32) s_b[t] = b_rel[t];

    int local = t >> 5;        // node within block
    int lane  = t & 31;        // embedding dim
    int node  = blockIdx.x * NODES_PER_BLOCK + local;   // always < 100000 (12500*8)

    float xv = x[node * EMBED + lane];
    int r0 = row_ptr[node], r1 = row_ptr[node + 1];
    int lim = r1 - 1;

    float acc[8];
    #pragma unroll
    for (int j = 0; j < 8; ++j) acc[j] = 0.f;

    for (int k = r0; k < r1; k += 8) {
        #pragma unroll
        for (int j = 0; j < 8; ++j) {
            int idx = k + j;
            int idc = (idx < lim) ? idx : lim;      // clamp: always a valid load
            int2 e  = epack[idc];
            float w = (idx <= lim) ? __int_as_float(e.y) : 0.f;
            acc[j] += w * x[e.x * EMBED + lane];
        }
    }
    float a = ((acc[0] + acc[1]) + (acc[2] + acc[3]))
            + ((acc[4] + acc[5]) + (acc[6] + acc[7]));

    s_agg[local * 33 + lane] = a;
    s_x[local * 33 + lane]   = xv;
    __syncthreads();

    float o = s_b[lane];
    #pragma unroll
    for (int d = 0; d < 32; ++d) {
        o += s_wrelT[d * 33 + lane] * s_agg[local * 33 + d]
           + s_wrootT[d * 33 + lane] * s_x[local * 33 + d];
    }
    o = (o >= 0.f) ? o : 0.01f * o;
    x_out[node * EMBED + lane] = o;
}

// ---------------- final pair MLP + log_softmax ----------------
__global__ void __launch_bounds__(256) mlp_kernel(
        const float* __restrict__ x,
        const int* __restrict__ home, const int* __restrict__ away,
        const float* __restrict__ w0, const float* __restrict__ b0,
        const float* __restrict__ w1, const float* __restrict__ b1,
        const float* __restrict__ w2, const float* __restrict__ b2,
        const float* __restrict__ w3, const float* __restrict__ b3,
        const float* __restrict__ w4, const float* __restrict__ b4,
        float* __restrict__ out, int n) {
    __shared__ float s_w0[512], s_w1[64], s_w2[64], s_w3[64], s_w4[24];
    __shared__ float s_b0[8], s_b1[8], s_b2[8], s_b3[8], s_b4[3];
    int t = threadIdx.x;
    for (int i = t; i < 512; i += 256) s_w0[i] = w0[i];
    if (t < 64) { s_w1[t] = w1[t]; s_w2[t] = w2[t]; s_w3[t] = w3[t]; }
    if (t < 24) s_w4[t] = w4[t];
    if (t < 8)  { s_b0[t] = b0[t]; s_b1[t] = b1[t]; s_b2[t] = b2[t]; s_b3[t] = b3[t]; }
    if (t < 3)  s_b4[t] = b4[t];
    __syncthreads();

    int i = blockIdx.x * 256 + t;
    if (i >= n) return;

    float hv[64];
    {
        const float4* ph = (const float4*)(x + (size_t)home[i] * EMBED);
        const float4* pa = (const float4*)(x + (size_t)away[i] * EMBED);
        #pragma unroll
        for (int q = 0; q < 8; ++q) {
            float4 v = ph[q];
            hv[4*q+0] = v.x; hv[4*q+1] = v.y; hv[4*q+2] = v.z; hv[4*q+3] = v.w;
        }
        #pragma unroll
        for (int q = 0; q < 8; ++q) {
            float4 v = pa[q];
            hv[32+4*q+0] = v.x; hv[32+4*q+1] = v.y; hv[32+4*q+2] = v.z; hv[32+4*q+3] = v.w;
        }
    }

    float h1[8];
    #pragma unroll
    for (int j = 0; j < 8; ++j) {
        float o = s_b0[j];
        #pragma unroll
        for (int d = 0; d < 64; ++d) o += s_w0[j * 64 + d] * hv[d];
        h1[j] = (o >= 0.f) ? o : 0.01f * o;
    }
    float h2[8];
    #pragma unroll
    for (int j = 0; j < 8; ++j) {
        float o = s_b1[j];
        #pragma unroll
        for (int d = 0; d < 8; ++d) o += s_w1[j * 8 + d] * h1[d];
        h2[j] = (o >= 0.f) ? o : 0.01f * o;
    }
    float h3[8];
    #pragma unroll
    for (int j = 0; j < 8; ++j) {
        float o = s_b2[j];
        #pragma unroll
        for (int d = 0; d < 8; ++d) o += s_w2[j * 8 + d] * h2[d];
        h3[j] = (o >= 0.f) ? o : 0.01f * o;
    }
    float h4[8];
    #pragma unroll
    for (int j = 0; j < 8; ++j) {
        float o = s_b3[j];
        #pragma unroll
        for (int d = 0; d < 8; ++d) o += s_w3[j * 8 + d] * h3[d];
        h4[j] = (o >= 0.f) ? o : 0.01f * o;
    }
    float f[3];
    #pragma unroll
    for (int j = 0; j < 3; ++j) {
        float o = s_b4[j];
        #pragma unroll
        for (int d = 0; d < 8; ++d) o += s_w4[j * 8 + d] * h4[d];
        f[j] = (o >= 0.f) ? o : 0.01f * o;
    }
    float m  = fmaxf(f[0], fmaxf(f[1], f[2]));
    float s  = expf(f[0] - m) + expf(f[1] - m) + expf(f[2] - m);
    float ls = logf(s);
    out[3 * i + 0] = f[0] - m - ls;
    out[3 * i + 1] = f[1] - m - ls;
    out[3 * i + 2] = f[2] - m - ls;
}

// ---------------- launch ----------------

extern "C" void kernel_launch(void* const* d_in, const int* in_sizes, int n_in,
                              void* d_out, int out_size, void* d_ws, size_t ws_size,
                              hipStream_t stream) {
    const int*   edge_index = (const int*)d_in[0];
    const int*   src   = edge_index;
    const int*   dst   = edge_index + N_EDGES;
    const float* ew    = (const float*)d_in[1];
    const int*   home  = (const int*)d_in[2];
    const int*   away  = (const int*)d_in[3];
    const float* embed = (const float*)d_in[4];
    const float* w_rel  = (const float*)d_in[5];
    const float* b_rel  = (const float*)d_in[6];
    const float* w_root = (const float*)d_in[7];
    const float* w0 = (const float*)d_in[8];  const float* b0 = (const float*)d_in[9];
    const float* w1 = (const float*)d_in[10]; const float* b1 = (const float*)d_in[11];
    const float* w2 = (const float*)d_in[12]; const float* b2 = (const float*)d_in[13];
    const float* w3 = (const float*)d_in[14]; const float* b3 = (const float*)d_in[15];
    const float* w4 = (const float*)d_in[16]; const float* b4 = (const float*)d_in[17];
    float* out = (float*)d_out;

    char* ws = (char*)d_ws;
    size_t off = 0;
    auto carve = [&](size_t bytes) -> void* {
        void* p = ws + off;
        off += (bytes + 255) & ~(size_t)255;
        return p;
    };
    int*   row_ptr = (int*)  carve((NUM_TEAMS + 1) * sizeof(int));
    int*   bhist   = (int*)  carve(NBUCK * sizeof(int));
    int*   bbase   = (int*)  carve((NBUCK + 1) * sizeof(int));
    int*   bcursor = (int*)  carve(NBUCK * sizeof(int));
    int2*  recs    = (int2*) carve((size_t)N_EDGES * sizeof(int2));   // dead after P3
    int2*  epack   = (int2*) carve((size_t)N_EDGES * sizeof(int2));
    float* x1      = (float*)recs;   // alias: conv outputs reuse recs region (12.8MB <= 16MB)
    float* x2      = (float*)carve((size_t)NUM_TEAMS * EMBED * sizeof(float));
    (void)ws_size; (void)in_sizes; (void)n_in; (void)out_size;

    const int conv_blocks = NUM_TEAMS / NODES_PER_BLOCK;   // 12500 exact
    const int mlp_blocks  = (BQ + 255) / 256;

    hipMemsetAsync(bhist, 0, NBUCK * sizeof(int), stream);
    bhist_kernel<<<P2_BLOCKS, 256, 0, stream>>>(dst, bhist, N_EDGES);
    bscan_kernel<<<1, 256, 0, stream>>>(bhist, bbase, bcursor, row_ptr);
    partition_kernel<<<P2_BLOCKS, 256, 0, stream>>>(src, dst, ew, bcursor, recs, N_EDGES);
    finalize_kernel<<<NBUCK, 256, 0, stream>>>(recs, bbase, row_ptr, epack);

    conv_kernel<<<conv_blocks, 256, 0, stream>>>(embed, row_ptr, epack,
        w_rel + 0 * 1024, b_rel + 0 * 32, w_root + 0 * 1024, x1, NUM_TEAMS);
    conv_kernel<<<conv_blocks, 256, 0, stream>>>(x1, row_ptr, epack,
        w_rel + 1 * 1024, b_rel + 1 * 32, w_root + 1 * 1024, x2, NUM_TEAMS);
    conv_kernel<<<conv_blocks, 256, 0, stream>>>(x2, row_ptr, epack,
        w_rel + 2 * 1024, b_rel + 2 * 32, w_root + 2 * 1024, x1, NUM_TEAMS);

    mlp_kernel<<<mlp_blocks, 256, 0, stream>>>(x1, home, away,
        w0, b0, w1, b1, w2, b2, w3, b3, w4, b4, out, BQ);
}

// Round 6
// 294.721 us; speedup vs baseline: 2.3209x; 1.3811x over previous
//
#include <hip/hip_runtime.h>
#include <hip/hip_fp16.h>

#define NUM_TEAMS 100000
#define EMBED     32
#define N_EDGES   2000000
#define BQ        524288
#define TARGET_DIM 3

// ---- bucket partition parameters ----
#define BSH    9                       // bucket = dst >> 9
#define BSPAN  512                     // dst values per bucket
#define NBUCK  ((NUM_TEAMS + BSPAN - 1) / BSPAN)   // 196
#define TILE   8192                    // edges per partition block
#define P2_BLOCKS ((N_EDGES + TILE - 1) / TILE)    // 245

// ---------------- P1: bucket histogram ----------------
__global__ void __launch_bounds__(256) bhist_kernel(const int* __restrict__ dst,
                                                    int* __restrict__ bhist, int n) {
    __shared__ int cnt[NBUCK];
    int t = threadIdx.x;
    for (int i = t; i < NBUCK; i += 256) cnt[i] = 0;
    __syncthreads();
    int base = blockIdx.x * TILE;
    for (int j = 0; j < TILE; j += 256) {
        int i = base + j + t;
        if (i < n) atomicAdd(&cnt[dst[i] >> BSH], 1);
    }
    __syncthreads();
    for (int i = t; i < NBUCK; i += 256) if (cnt[i]) atomicAdd(&bhist[i], cnt[i]);
}

// ---------------- P1b: scan bucket counts (1 block) ----------------
__global__ void __launch_bounds__(256) bscan_kernel(const int* __restrict__ bhist,
                                                    int* __restrict__ bbase,
                                                    int* __restrict__ bcursor,
                                                    int* __restrict__ row_ptr) {
    __shared__ int wsum[4];
    int t = threadIdx.x;
    int v = (t < NBUCK) ? bhist[t] : 0;
    int lane = t & 63, wid = t >> 6;
    int incl = v;
    #pragma unroll
    for (int off = 1; off < 64; off <<= 1) {
        int u = __shfl_up(incl, off, 64);
        if (lane >= off) incl += u;
    }
    if (lane == 63) wsum[wid] = incl;
    __syncthreads();
    int wofs = 0;
    for (int w = 0; w < wid; ++w) wofs += wsum[w];
    int excl = incl - v + wofs;
    if (t < NBUCK) { bbase[t] = excl; bcursor[t] = excl; }
    if (t == 0) { bbase[NBUCK] = N_EDGES; row_ptr[NUM_TEAMS] = N_EDGES; }
}

// ---------------- P2: chunked partition into bucket regions ----------------
// rec.x = src | (dst_local << 17)
__global__ void __launch_bounds__(256) partition_kernel(
        const int* __restrict__ src, const int* __restrict__ dst,
        const float* __restrict__ ew,
        int* __restrict__ bcursor, int2* __restrict__ recs, int n) {
    __shared__ int cnt[NBUCK];
    __shared__ int lbase[NBUCK];
    int t = threadIdx.x;
    for (int i = t; i < NBUCK; i += 256) cnt[i] = 0;
    __syncthreads();
    int base = blockIdx.x * TILE;
    for (int j = 0; j < TILE; j += 256) {
        int i = base + j + t;
        if (i < n) atomicAdd(&cnt[dst[i] >> BSH], 1);
    }
    __syncthreads();
    for (int b = t; b < NBUCK; b += 256) {
        int c = cnt[b];
        lbase[b] = c ? atomicAdd(&bcursor[b], c) : 0;
        cnt[b] = 0;                    // reuse as local cursor
    }
    __syncthreads();
    for (int j = 0; j < TILE; j += 256) {
        int i = base + j + t;
        if (i < n) {
            int d = dst[i];
            int b = d >> BSH;
            int r = atomicAdd(&cnt[b], 1);
            int2 rec;
            rec.x = src[i] | ((d & (BSPAN - 1)) << 17);
            rec.y = __float_as_int(ew[i]);
            recs[lbase[b] + r] = rec;
        }
    }
}

// ---------------- P3: per-bucket CSR finalize ----------------
__global__ void __launch_bounds__(256) finalize_kernel(
        const int2* __restrict__ recs, const int* __restrict__ bbase,
        int* __restrict__ row_ptr, int2* __restrict__ epack) {
    __shared__ int cnt[BSPAN];
    __shared__ int excl[BSPAN];
    int b = blockIdx.x;
    int t = threadIdx.x;
    int rbase = bbase[b], rend = bbase[b + 1];
    for (int i = t; i < BSPAN; i += 256) cnt[i] = 0;
    __syncthreads();
    for (int k = rbase + t; k < rend; k += 256)
        atomicAdd(&cnt[recs[k].x >> 17], 1);
    __syncthreads();
    if (t < 64) {
        int c[8]; int s = 0;
        #pragma unroll
        for (int k = 0; k < 8; ++k) { c[k] = cnt[t * 8 + k]; s += c[k]; }
        int incl = s;
        #pragma unroll
        for (int off = 1; off < 64; off <<= 1) {
            int u = __shfl_up(incl, off, 64);
            if (t >= off) incl += u;
        }
        int e = incl - s;
        #pragma unroll
        for (int k = 0; k < 8; ++k) { excl[t * 8 + k] = e; e += c[k]; }
    }
    __syncthreads();
    for (int i = t; i < BSPAN; i += 256) {
        int node = b * BSPAN + i;
        if (node < NUM_TEAMS) row_ptr[node] = rbase + excl[i];
        cnt[i] = excl[i];              // reuse as cursor
    }
    __syncthreads();
    for (int k = rbase + t; k < rend; k += 256) {
        int2 rec = recs[k];
        int dloc = rec.x >> 17;
        int r = atomicAdd(&cnt[dloc], 1);
        int2 e; e.x = rec.x & 0x1FFFF; e.y = rec.y;
        epack[rbase + r] = e;
    }
}

// ---------------- f32 -> fp16 convert ----------------
__global__ void __launch_bounds__(256) cvt_kernel(const float* __restrict__ in,
                                                  __half* __restrict__ out, int n2) {
    int i = blockIdx.x * 256 + threadIdx.x;   // i indexes pairs
    if (i < n2) {
        float2 v = *(const float2*)(in + 2 * i);
        *(__half2*)(out + 2 * i) = __floats2half2_rn(v.x, v.y);
    }
}

// ---------------- fused GraphConv layer (fp16 storage, f32 math) ----------------
// block = 256 threads = 8 nodes x 32 lanes. lane = embedding dim.
#define NODES_PER_BLOCK 8
__global__ void __launch_bounds__(256) conv_kernel(
        const __half* __restrict__ xh,
        const int* __restrict__ row_ptr,
        const int2* __restrict__ epack,
        const float* __restrict__ w_rel,   // [32][32] row-major
        const float* __restrict__ b_rel,   // [32]
        const float* __restrict__ w_root,  // [32][32]
        __half* __restrict__ x_out, int num_nodes) {
    __shared__ float s_wrelT[32 * 33];   // transposed+padded
    __shared__ float s_wrootT[32 * 33];
    __shared__ float s_b[32];
    __shared__ float s_agg[NODES_PER_BLOCK * 33];
    __shared__ float s_x[NODES_PER_BLOCK * 33];

    int t = threadIdx.x;
    for (int i = t; i < 1024; i += 256) {
        int j = i >> 5, d = i & 31;
        s_wrelT[d * 33 + j]  = w_rel[i];
        s_wrootT[d * 33 + j] = w_root[i];
    }
    if (t < 32) s_b[t] = b_rel[t];

    int local = t >> 5;
    int lane  = t & 31;
    int node  = blockIdx.x * NODES_PER_BLOCK + local;   // 100000 = 12500*8 exact

    float xv = __half2float(xh[node * EMBED + lane]);
    int r0 = row_ptr[node], r1 = row_ptr[node + 1];
    int lim = r1 - 1;

    float acc[8];
    #pragma unroll
    for (int j = 0; j < 8; ++j) acc[j] = 0.f;

    for (int k = r0; k < r1; k += 8) {
        int2 e[8];
        #pragma unroll
        for (int j = 0; j < 8; ++j) {
            int idx = k + j;
            e[j] = epack[(idx < lim) ? idx : lim];
        }
        float g[8];
        #pragma unroll
        for (int j = 0; j < 8; ++j) {
            g[j] = __half2float(xh[e[j].x * EMBED + lane]);
        }
        #pragma unroll
        for (int j = 0; j < 8; ++j) {
            float w = (k + j <= lim) ? __int_as_float(e[j].y) : 0.f;
            acc[j] += w * g[j];
        }
    }
    float a = ((acc[0] + acc[1]) + (acc[2] + acc[3]))
            + ((acc[4] + acc[5]) + (acc[6] + acc[7]));

    s_agg[local * 33 + lane] = a;
    s_x[local * 33 + lane]   = xv;
    __syncthreads();

    float o = s_b[lane];
    #pragma unroll
    for (int d = 0; d < 32; ++d) {
        o += s_wrelT[d * 33 + lane] * s_agg[local * 33 + d]
           + s_wrootT[d * 33 + lane] * s_x[local * 33 + d];
    }
    o = (o >= 0.f) ? o : 0.01f * o;
    x_out[node * EMBED + lane] = __float2half(o);
}

// ---------------- final pair MLP + log_softmax ----------------
__global__ void __launch_bounds__(256) mlp_kernel(
        const __half* __restrict__ xh,
        const int* __restrict__ home, const int* __restrict__ away,
        const float* __restrict__ w0, const float* __restrict__ b0,
        const float* __restrict__ w1, const float* __restrict__ b1,
        const float* __restrict__ w2, const float* __restrict__ b2,
        const float* __restrict__ w3, const float* __restrict__ b3,
        const float* __restrict__ w4, const float* __restrict__ b4,
        float* __restrict__ out, int n) {
    __shared__ float s_w0[512], s_w1[64], s_w2[64], s_w3[64], s_w4[24];
    __shared__ float s_b0[8], s_b1[8], s_b2[8], s_b3[8], s_b4[3];
    int t = threadIdx.x;
    for (int i = t; i < 512; i += 256) s_w0[i] = w0[i];
    if (t < 64) { s_w1[t] = w1[t]; s_w2[t] = w2[t]; s_w3[t] = w3[t]; }
    if (t < 24) s_w4[t] = w4[t];
    if (t < 8)  { s_b0[t] = b0[t]; s_b1[t] = b1[t]; s_b2[t] = b2[t]; s_b3[t] = b3[t]; }
    if (t < 3)  s_b4[t] = b4[t];
    __syncthreads();

    int i = blockIdx.x * 256 + t;
    if (i >= n) return;

    float hv[64];
    {
        const __half2* ph = (const __half2*)(xh + (size_t)home[i] * EMBED);
        const __half2* pa = (const __half2*)(xh + (size_t)away[i] * EMBED);
        #pragma unroll
        for (int q = 0; q < 16; ++q) {
            float2 f = __half22float2(ph[q]);
            hv[2*q+0] = f.x; hv[2*q+1] = f.y;
        }
        #pragma unroll
        for (int q = 0; q < 16; ++q) {
            float2 f = __half22float2(pa[q]);
            hv[32+2*q+0] = f.x; hv[32+2*q+1] = f.y;
        }
    }

    float h1[8];
    #pragma unroll
    for (int j = 0; j < 8; ++j) {
        float o = s_b0[j];
        #pragma unroll
        for (int d = 0; d < 64; ++d) o += s_w0[j * 64 + d] * hv[d];
        h1[j] = (o >= 0.f) ? o : 0.01f * o;
    }
    float h2[8];
    #pragma unroll
    for (int j = 0; j < 8; ++j) {
        float o = s_b1[j];
        #pragma unroll
        for (int d = 0; d < 8; ++d) o += s_w1[j * 8 + d] * h1[d];
        h2[j] = (o >= 0.f) ? o : 0.01f * o;
    }
    float h3[8];
    #pragma unroll
    for (int j = 0; j < 8; ++j) {
        float o = s_b2[j];
        #pragma unroll
        for (int d = 0; d < 8; ++d) o += s_w2[j * 8 + d] * h2[d];
        h3[j] = (o >= 0.f) ? o : 0.01f * o;
    }
    float h4[8];
    #pragma unroll
    for (int j = 0; j < 8; ++j) {
        float o = s_b3[j];
        #pragma unroll
        for (int d = 0; d < 8; ++d) o += s_w3[j * 8 + d] * h3[d];
        h4[j] = (o >= 0.f) ? o : 0.01f * o;
    }
    float f[3];
    #pragma unroll
    for (int j = 0; j < 3; ++j) {
        float o = s_b4[j];
        #pragma unroll
        for (int d = 0; d < 8; ++d) o += s_w4[j * 8 + d] * h4[d];
        f[j] = (o >= 0.f) ? o : 0.01f * o;
    }
    float m  = fmaxf(f[0], fmaxf(f[1], f[2]));
    float s  = expf(f[0] - m) + expf(f[1] - m) + expf(f[2] - m);
    float ls = logf(s);
    out[3 * i + 0] = f[0] - m - ls;
    out[3 * i + 1] = f[1] - m - ls;
    out[3 * i + 2] = f[2] - m - ls;
}

// ---------------- launch ----------------

extern "C" void kernel_launch(void* const* d_in, const int* in_sizes, int n_in,
                              void* d_out, int out_size, void* d_ws, size_t ws_size,
                              hipStream_t stream) {
    const int*   edge_index = (const int*)d_in[0];
    const int*   src   = edge_index;
    const int*   dst   = edge_index + N_EDGES;
    const float* ew    = (const float*)d_in[1];
    const int*   home  = (const int*)d_in[2];
    const int*   away  = (const int*)d_in[3];
    const float* embed = (const float*)d_in[4];
    const float* w_rel  = (const float*)d_in[5];
    const float* b_rel  = (const float*)d_in[6];
    const float* w_root = (const float*)d_in[7];
    const float* w0 = (const float*)d_in[8];  const float* b0 = (const float*)d_in[9];
    const float* w1 = (const float*)d_in[10]; const float* b1 = (const float*)d_in[11];
    const float* w2 = (const float*)d_in[12]; const float* b2 = (const float*)d_in[13];
    const float* w3 = (const float*)d_in[14]; const float* b3 = (const float*)d_in[15];
    const float* w4 = (const float*)d_in[16]; const float* b4 = (const float*)d_in[17];
    float* out = (float*)d_out;

    char* ws = (char*)d_ws;
    size_t off = 0;
    auto carve = [&](size_t bytes) -> void* {
        void* p = ws + off;
        off += (bytes + 255) & ~(size_t)255;
        return p;
    };
    int*   row_ptr = (int*)  carve((NUM_TEAMS + 1) * sizeof(int));
    int*   bhist   = (int*)  carve(NBUCK * sizeof(int));
    int*   bbase   = (int*)  carve((NBUCK + 1) * sizeof(int));
    int*   bcursor = (int*)  carve(NBUCK * sizeof(int));
    int2*  recs    = (int2*) carve((size_t)N_EDGES * sizeof(int2));   // dead after P3
    int2*  epack   = (int2*) carve((size_t)N_EDGES * sizeof(int2));
    // fp16 node-feature buffers: embedh + x1h alias the dead recs region (12.8MB <= 16MB)
    __half* embedh = (__half*)recs;
    __half* x1h    = (__half*)recs + (size_t)NUM_TEAMS * EMBED;
    __half* x2h    = (__half*)carve((size_t)NUM_TEAMS * EMBED * sizeof(__half));
    (void)ws_size; (void)in_sizes; (void)n_in; (void)out_size;

    const int conv_blocks = NUM_TEAMS / NODES_PER_BLOCK;   // 12500 exact
    const int mlp_blocks  = (BQ + 255) / 256;
    const int cvt_pairs   = NUM_TEAMS * EMBED / 2;         // 1.6M half2 pairs

    hipMemsetAsync(bhist, 0, NBUCK * sizeof(int), stream);
    bhist_kernel<<<P2_BLOCKS, 256, 0, stream>>>(dst, bhist, N_EDGES);
    bscan_kernel<<<1, 256, 0, stream>>>(bhist, bbase, bcursor, row_ptr);
    partition_kernel<<<P2_BLOCKS, 256, 0, stream>>>(src, dst, ew, bcursor, recs, N_EDGES);
    finalize_kernel<<<NBUCK, 256, 0, stream>>>(recs, bbase, row_ptr, epack);
    // recs is dead now -> safe to overwrite with embedh/x1h
    cvt_kernel<<<(cvt_pairs + 255) / 256, 256, 0, stream>>>(embed, embedh, cvt_pairs);

    conv_kernel<<<conv_blocks, 256, 0, stream>>>(embedh, row_ptr, epack,
        w_rel + 0 * 1024, b_rel + 0 * 32, w_root + 0 * 1024, x2h, NUM_TEAMS);
    conv_kernel<<<conv_blocks, 256, 0, stream>>>(x2h, row_ptr, epack,
        w_rel + 1 * 1024, b_rel + 1 * 32, w_root + 1 * 1024, x1h, NUM_TEAMS);
    conv_kernel<<<conv_blocks, 256, 0, stream>>>(x1h, row_ptr, epack,
        w_rel + 2 * 1024, b_rel + 2 * 32, w_root + 2 * 1024, x2h, NUM_TEAMS);

    mlp_kernel<<<mlp_blocks, 256, 0, stream>>>(x2h, home, away,
        w0, b0, w1, b1, w2, b2, w3, b3, w4, b4, out, BQ);
}

// Round 7
// 267.073 us; speedup vs baseline: 2.5612x; 1.1035x over previous
//
#include <hip/hip_runtime.h>
#include <hip/hip_fp16.h>

#define NUM_TEAMS 100000
#define EMBED     32
#define N_EDGES   2000000
#define BQ        524288
#define TARGET_DIM 3

// ---- bucket partition parameters ----
#define BSH    9
#define BSPAN  512
#define NBUCK  ((NUM_TEAMS + BSPAN - 1) / BSPAN)   // 196
#define TILE   8192
#define P2_BLOCKS ((N_EDGES + TILE - 1) / TILE)    // 245

// ---------------- P1: bucket histogram ----------------
__global__ void __launch_bounds__(256) bhist_kernel(const int* __restrict__ dst,
                                                    int* __restrict__ bhist, int n) {
    __shared__ int cnt[NBUCK];
    int t = threadIdx.x;
    for (int i = t; i < NBUCK; i += 256) cnt[i] = 0;
    __syncthreads();
    int base = blockIdx.x * TILE;
    for (int j = 0; j < TILE; j += 256) {
        int i = base + j + t;
        if (i < n) atomicAdd(&cnt[dst[i] >> BSH], 1);
    }
    __syncthreads();
    for (int i = t; i < NBUCK; i += 256) if (cnt[i]) atomicAdd(&bhist[i], cnt[i]);
}

// ---------------- P1b: scan bucket counts (1 block) ----------------
__global__ void __launch_bounds__(256) bscan_kernel(const int* __restrict__ bhist,
                                                    int* __restrict__ bbase,
                                                    int* __restrict__ bcursor,
                                                    int* __restrict__ row_ptr) {
    __shared__ int wsum[4];
    int t = threadIdx.x;
    int v = (t < NBUCK) ? bhist[t] : 0;
    int lane = t & 63, wid = t >> 6;
    int incl = v;
    #pragma unroll
    for (int off = 1; off < 64; off <<= 1) {
        int u = __shfl_up(incl, off, 64);
        if (lane >= off) incl += u;
    }
    if (lane == 63) wsum[wid] = incl;
    __syncthreads();
    int wofs = 0;
    for (int w = 0; w < wid; ++w) wofs += wsum[w];
    int excl = incl - v + wofs;
    if (t < NBUCK) { bbase[t] = excl; bcursor[t] = excl; }
    if (t == 0) { bbase[NBUCK] = N_EDGES; row_ptr[NUM_TEAMS] = N_EDGES; }
}

// ---------------- P2: chunked partition into bucket regions ----------------
__global__ void __launch_bounds__(256) partition_kernel(
        const int* __restrict__ src, const int* __restrict__ dst,
        const float* __restrict__ ew,
        int* __restrict__ bcursor, int2* __restrict__ recs, int n) {
    __shared__ int cnt[NBUCK];
    __shared__ int lbase[NBUCK];
    int t = threadIdx.x;
    for (int i = t; i < NBUCK; i += 256) cnt[i] = 0;
    __syncthreads();
    int base = blockIdx.x * TILE;
    for (int j = 0; j < TILE; j += 256) {
        int i = base + j + t;
        if (i < n) atomicAdd(&cnt[dst[i] >> BSH], 1);
    }
    __syncthreads();
    for (int b = t; b < NBUCK; b += 256) {
        int c = cnt[b];
        lbase[b] = c ? atomicAdd(&bcursor[b], c) : 0;
        cnt[b] = 0;
    }
    __syncthreads();
    for (int j = 0; j < TILE; j += 256) {
        int i = base + j + t;
        if (i < n) {
            int d = dst[i];
            int b = d >> BSH;
            int r = atomicAdd(&cnt[b], 1);
            int2 rec;
            rec.x = src[i] | ((d & (BSPAN - 1)) << 17);
            rec.y = __float_as_int(ew[i]);
            recs[lbase[b] + r] = rec;
        }
    }
}

// ---------------- P3: per-bucket CSR finalize ----------------
__global__ void __launch_bounds__(256) finalize_kernel(
        const int2* __restrict__ recs, const int* __restrict__ bbase,
        int* __restrict__ row_ptr, int2* __restrict__ epack) {
    __shared__ int cnt[BSPAN];
    __shared__ int excl[BSPAN];
    int b = blockIdx.x;
    int t = threadIdx.x;
    int rbase = bbase[b], rend = bbase[b + 1];
    for (int i = t; i < BSPAN; i += 256) cnt[i] = 0;
    __syncthreads();
    for (int k = rbase + t; k < rend; k += 256)
        atomicAdd(&cnt[recs[k].x >> 17], 1);
    __syncthreads();
    if (t < 64) {
        int c[8]; int s = 0;
        #pragma unroll
        for (int k = 0; k < 8; ++k) { c[k] = cnt[t * 8 + k]; s += c[k]; }
        int incl = s;
        #pragma unroll
        for (int off = 1; off < 64; off <<= 1) {
            int u = __shfl_up(incl, off, 64);
            if (t >= off) incl += u;
        }
        int e = incl - s;
        #pragma unroll
        for (int k = 0; k < 8; ++k) { excl[t * 8 + k] = e; e += c[k]; }
    }
    __syncthreads();
    for (int i = t; i < BSPAN; i += 256) {
        int node = b * BSPAN + i;
        if (node < NUM_TEAMS) row_ptr[node] = rbase + excl[i];
        cnt[i] = excl[i];
    }
    __syncthreads();
    for (int k = rbase + t; k < rend; k += 256) {
        int2 rec = recs[k];
        int dloc = rec.x >> 17;
        int r = atomicAdd(&cnt[dloc], 1);
        int2 e; e.x = rec.x & 0x1FFFF; e.y = rec.y;
        epack[rbase + r] = e;
    }
}

// ---------------- f32 -> fp16 convert ----------------
__global__ void __launch_bounds__(256) cvt_kernel(const float* __restrict__ in,
                                                  __half* __restrict__ out, int n2) {
    int i = blockIdx.x * 256 + threadIdx.x;
    if (i < n2) {
        float2 v = *(const float2*)(in + 2 * i);
        *(__half2*)(out + 2 * i) = __floats2half2_rn(v.x, v.y);
    }
}

// ---------------- fused GraphConv (16 lanes/node, half2 lanes) ----------------
// block = 256 threads = 16 nodes x 16 lanes; lane l covers dims {2l, 2l+1}.
// Gather: half2 (4B/lane, 64B/row). Accumulate: v_pk_fma_f16. Transform: f32.
#define CONV_NPB 16
__global__ void __launch_bounds__(256) conv_kernel(
        const __half* __restrict__ xh,
        const int* __restrict__ row_ptr,
        const int2* __restrict__ epack,
        const float* __restrict__ w_rel,   // [32][32] row-major
        const float* __restrict__ b_rel,   // [32]
        const float* __restrict__ w_root,  // [32][32]
        __half* __restrict__ x_out) {
    __shared__ float s_wrelT[32 * 33];   // [d][j] at d*33+j (pad kills staging conflict)
    __shared__ float s_wrootT[32 * 33];
    __shared__ float s_b[32];
    __shared__ float s_agg[CONV_NPB][34];  // even stride -> float2 LDS ops, 2-way max
    __shared__ float s_x[CONV_NPB][34];

    int t = threadIdx.x;
    for (int i = t; i < 1024; i += 256) {
        int j = i >> 5, d = i & 31;
        s_wrelT[d * 33 + j]  = w_rel[i];
        s_wrootT[d * 33 + j] = w_root[i];
    }
    if (t < 32) s_b[t] = b_rel[t];

    int ln = t >> 4;           // node within block
    int l  = t & 15;           // dim-pair index
    int node = blockIdx.x * CONV_NPB + ln;   // 100000 = 6250*16 exact

    const __half2* xh2 = (const __half2*)xh;
    float2 xv = __half22float2(xh2[node * 16 + l]);
    int r0 = row_ptr[node], r1 = row_ptr[node + 1];
    int lim = r1 - 1;

    __half2 acc[8];
    #pragma unroll
    for (int j = 0; j < 8; ++j) acc[j] = __floats2half2_rn(0.f, 0.f);

    for (int k = r0; k < r1; k += 8) {
        int sx[8]; float wv[8];
        #pragma unroll
        for (int j = 0; j < 8; ++j) {
            int idx = k + j;
            idx = idx < lim ? idx : lim;               // clamp: always valid
            long long raw = __builtin_nontemporal_load(
                                (const long long*)(epack + idx));
            sx[j] = (int)(unsigned)(raw & 0xffffffffll);
            wv[j] = __int_as_float((int)(raw >> 32));
        }
        __half2 g[8];
        #pragma unroll
        for (int j = 0; j < 8; ++j) g[j] = xh2[sx[j] * 16 + l];
        #pragma unroll
        for (int j = 0; j < 8; ++j) {
            float w = (k + j <= lim) ? wv[j] : 0.f;
            __half2 w2 = __floats2half2_rn(w, w);
            acc[j] = __hfma2(w2, g[j], acc[j]);
        }
    }
    float2 a = {0.f, 0.f};
    #pragma unroll
    for (int j = 0; j < 8; ++j) {
        float2 f = __half22float2(acc[j]);
        a.x += f.x; a.y += f.y;
    }
    *(float2*)&s_agg[ln][2 * l] = a;
    *(float2*)&s_x[ln][2 * l]   = xv;
    __syncthreads();

    int j0 = 2 * l, j1 = 2 * l + 1;
    float o0 = s_b[j0], o1 = s_b[j1];
    #pragma unroll
    for (int d = 0; d < 32; ++d) {
        float ag = s_agg[ln][d];                 // broadcast across 16 lanes
        float xx = s_x[ln][d];
        o0 += s_wrelT[d * 33 + j0] * ag + s_wrootT[d * 33 + j0] * xx;
        o1 += s_wrelT[d * 33 + j1] * ag + s_wrootT[d * 33 + j1] * xx;
    }
    o0 = (o0 >= 0.f) ? o0 : 0.01f * o0;
    o1 = (o1 >= 0.f) ? o1 : 0.01f * o1;
    ((__half2*)x_out)[node * 16 + l] = __floats2half2_rn(o0, o1);
}

// ---------------- final pair MLP + log_softmax ----------------
__global__ void __launch_bounds__(256) mlp_kernel(
        const __half* __restrict__ xh,
        const int* __restrict__ home, const int* __restrict__ away,
        const float* __restrict__ w0, const float* __restrict__ b0,
        const float* __restrict__ w1, const float* __restrict__ b1,
        const float* __restrict__ w2, const float* __restrict__ b2,
        const float* __restrict__ w3, const float* __restrict__ b3,
        const float* __restrict__ w4, const float* __restrict__ b4,
        float* __restrict__ out, int n) {
    __shared__ float s_w0[512], s_w1[64], s_w2[64], s_w3[64], s_w4[24];
    __shared__ float s_b0[8], s_b1[8], s_b2[8], s_b3[8], s_b4[3];
    int t = threadIdx.x;
    for (int i = t; i < 512; i += 256) s_w0[i] = w0[i];
    if (t < 64) { s_w1[t] = w1[t]; s_w2[t] = w2[t]; s_w3[t] = w3[t]; }
    if (t < 24) s_w4[t] = w4[t];
    if (t < 8)  { s_b0[t] = b0[t]; s_b1[t] = b1[t]; s_b2[t] = b2[t]; s_b3[t] = b3[t]; }
    if (t < 3)  s_b4[t] = b4[t];
    __syncthreads();

    int i = blockIdx.x * 256 + t;
    if (i >= n) return;

    int hi = __builtin_nontemporal_load(home + i);
    int ai = __builtin_nontemporal_load(away + i);

    float hv[64];
    {
        const __half2* ph = (const __half2*)(xh + (size_t)hi * EMBED);
        const __half2* pa = (const __half2*)(xh + (size_t)ai * EMBED);
        #pragma unroll
        for (int q = 0; q < 16; ++q) {
            float2 f = __half22float2(ph[q]);
            hv[2*q+0] = f.x; hv[2*q+1] = f.y;
        }
        #pragma unroll
        for (int q = 0; q < 16; ++q) {
            float2 f = __half22float2(pa[q]);
            hv[32+2*q+0] = f.x; hv[32+2*q+1] = f.y;
        }
    }

    float h1[8];
    #pragma unroll
    for (int j = 0; j < 8; ++j) {
        float o = s_b0[j];
        #pragma unroll
        for (int d = 0; d < 64; ++d) o += s_w0[j * 64 + d] * hv[d];
        h1[j] = (o >= 0.f) ? o : 0.01f * o;
    }
    float h2[8];
    #pragma unroll
    for (int j = 0; j < 8; ++j) {
        float o = s_b1[j];
        #pragma unroll
        for (int d = 0; d < 8; ++d) o += s_w1[j * 8 + d] * h1[d];
        h2[j] = (o >= 0.f) ? o : 0.01f * o;
    }
    float h3[8];
    #pragma unroll
    for (int j = 0; j < 8; ++j) {
        float o = s_b2[j];
        #pragma unroll
        for (int d = 0; d < 8; ++d) o += s_w2[j * 8 + d] * h2[d];
        h3[j] = (o >= 0.f) ? o : 0.01f * o;
    }
    float h4[8];
    #pragma unroll
    for (int j = 0; j < 8; ++j) {
        float o = s_b3[j];
        #pragma unroll
        for (int d = 0; d < 8; ++d) o += s_w3[j * 8 + d] * h3[d];
        h4[j] = (o >= 0.f) ? o : 0.01f * o;
    }
    float f[3];
    #pragma unroll
    for (int j = 0; j < 3; ++j) {
        float o = s_b4[j];
        #pragma unroll
        for (int d = 0; d < 8; ++d) o += s_w4[j * 8 + d] * h4[d];
        f[j] = (o >= 0.f) ? o : 0.01f * o;
    }
    float m  = fmaxf(f[0], fmaxf(f[1], f[2]));
    float s  = expf(f[0] - m) + expf(f[1] - m) + expf(f[2] - m);
    float ls = logf(s);
    out[3 * i + 0] = f[0] - m - ls;
    out[3 * i + 1] = f[1] - m - ls;
    out[3 * i + 2] = f[2] - m - ls;
}

// ---------------- launch ----------------

extern "C" void kernel_launch(void* const* d_in, const int* in_sizes, int n_in,
                              void* d_out, int out_size, void* d_ws, size_t ws_size,
                              hipStream_t stream) {
    const int*   edge_index = (const int*)d_in[0];
    const int*   src   = edge_index;
    const int*   dst   = edge_index + N_EDGES;
    const float* ew    = (const float*)d_in[1];
    const int*   home  = (const int*)d_in[2];
    const int*   away  = (const int*)d_in[3];
    const float* embed = (const float*)d_in[4];
    const float* w_rel  = (const float*)d_in[5];
    const float* b_rel  = (const float*)d_in[6];
    const float* w_root = (const float*)d_in[7];
    const float* w0 = (const float*)d_in[8];  const float* b0 = (const float*)d_in[9];
    const float* w1 = (const float*)d_in[10]; const float* b1 = (const float*)d_in[11];
    const float* w2 = (const float*)d_in[12]; const float* b2 = (const float*)d_in[13];
    const float* w3 = (const float*)d_in[14]; const float* b3 = (const float*)d_in[15];
    const float* w4 = (const float*)d_in[16]; const float* b4 = (const float*)d_in[17];
    float* out = (float*)d_out;

    char* ws = (char*)d_ws;
    size_t off = 0;
    auto carve = [&](size_t bytes) -> void* {
        void* p = ws + off;
        off += (bytes + 255) & ~(size_t)255;
        return p;
    };
    int*   row_ptr = (int*)  carve((NUM_TEAMS + 1) * sizeof(int));
    int*   bhist   = (int*)  carve(NBUCK * sizeof(int));
    int*   bbase   = (int*)  carve((NBUCK + 1) * sizeof(int));
    int*   bcursor = (int*)  carve(NBUCK * sizeof(int));
    int2*  recs    = (int2*) carve((size_t)N_EDGES * sizeof(int2));   // dead after P3
    int2*  epack   = (int2*) carve((size_t)N_EDGES * sizeof(int2));
    __half* embedh = (__half*)recs;                           // alias dead recs
    __half* x1h    = (__half*)recs + (size_t)NUM_TEAMS * EMBED;
    __half* x2h    = (__half*)carve((size_t)NUM_TEAMS * EMBED * sizeof(__half));
    (void)ws_size; (void)in_sizes; (void)n_in; (void)out_size;

    const int conv_blocks = NUM_TEAMS / CONV_NPB;   // 6250 exact
    const int mlp_blocks  = (BQ + 255) / 256;
    const int cvt_pairs   = NUM_TEAMS * EMBED / 2;

    hipMemsetAsync(bhist, 0, NBUCK * sizeof(int), stream);
    bhist_kernel<<<P2_BLOCKS, 256, 0, stream>>>(dst, bhist, N_EDGES);
    bscan_kernel<<<1, 256, 0, stream>>>(bhist, bbase, bcursor, row_ptr);
    partition_kernel<<<P2_BLOCKS, 256, 0, stream>>>(src, dst, ew, bcursor, recs, N_EDGES);
    finalize_kernel<<<NBUCK, 256, 0, stream>>>(recs, bbase, row_ptr, epack);
    cvt_kernel<<<(cvt_pairs + 255) / 256, 256, 0, stream>>>(embed, embedh, cvt_pairs);

    conv_kernel<<<conv_blocks, 256, 0, stream>>>(embedh, row_ptr, epack,
        w_rel + 0 * 1024, b_rel + 0 * 32, w_root + 0 * 1024, x2h);
    conv_kernel<<<conv_blocks, 256, 0, stream>>>(x2h, row_ptr, epack,
        w_rel + 1 * 1024, b_rel + 1 * 32, w_root + 1 * 1024, x1h);
    conv_kernel<<<conv_blocks, 256, 0, stream>>>(x1h, row_ptr, epack,
        w_rel + 2 * 1024, b_rel + 2 * 32, w_root + 2 * 1024, x2h);

    mlp_kernel<<<mlp_blocks, 256, 0, stream>>>(x2h, home, away,
        w0, b0, w1, b1, w2, b2, w3, b3, w4, b4, out, BQ);
}

// Round 8
// 251.308 us; speedup vs baseline: 2.7218x; 1.0627x over previous
//
#include <hip/hip_runtime.h>
#include <hip/hip_fp16.h>

#define NUM_TEAMS 100000
#define EMBED     32
#define N_EDGES   2000000
#define BQ        524288
#define TARGET_DIM 3

// ---- bucket partition parameters ----
#define BSH    9
#define BSPAN  512
#define NBUCK  ((NUM_TEAMS + BSPAN - 1) / BSPAN)   // 196
#define TILE   8192
#define P2_BLOCKS ((N_EDGES + TILE - 1) / TILE)    // 245

// ---------------- P1: bucket histogram ----------------
__global__ void __launch_bounds__(256) bhist_kernel(const int* __restrict__ dst,
                                                    int* __restrict__ bhist, int n) {
    __shared__ int cnt[NBUCK];
    int t = threadIdx.x;
    for (int i = t; i < NBUCK; i += 256) cnt[i] = 0;
    __syncthreads();
    int base = blockIdx.x * TILE;
    for (int j = 0; j < TILE; j += 256) {
        int i = base + j + t;
        if (i < n) atomicAdd(&cnt[dst[i] >> BSH], 1);
    }
    __syncthreads();
    for (int i = t; i < NBUCK; i += 256) if (cnt[i]) atomicAdd(&bhist[i], cnt[i]);
}

// ---------------- P1b: scan bucket counts (1 block) ----------------
__global__ void __launch_bounds__(256) bscan_kernel(const int* __restrict__ bhist,
                                                    int* __restrict__ bbase,
                                                    int* __restrict__ bcursor,
                                                    int* __restrict__ row_ptr) {
    __shared__ int wsum[4];
    int t = threadIdx.x;
    int v = (t < NBUCK) ? bhist[t] : 0;
    int lane = t & 63, wid = t >> 6;
    int incl = v;
    #pragma unroll
    for (int off = 1; off < 64; off <<= 1) {
        int u = __shfl_up(incl, off, 64);
        if (lane >= off) incl += u;
    }
    if (lane == 63) wsum[wid] = incl;
    __syncthreads();
    int wofs = 0;
    for (int w = 0; w < wid; ++w) wofs += wsum[w];
    int excl = incl - v + wofs;
    if (t < NBUCK) { bbase[t] = excl; bcursor[t] = excl; }
    if (t == 0) { bbase[NBUCK] = N_EDGES; row_ptr[NUM_TEAMS] = N_EDGES; }
}

// ---------------- P2: chunked partition into bucket regions ----------------
__global__ void __launch_bounds__(256) partition_kernel(
        const int* __restrict__ src, const int* __restrict__ dst,
        const float* __restrict__ ew,
        int* __restrict__ bcursor, int2* __restrict__ recs, int n) {
    __shared__ int cnt[NBUCK];
    __shared__ int lbase[NBUCK];
    int t = threadIdx.x;
    for (int i = t; i < NBUCK; i += 256) cnt[i] = 0;
    __syncthreads();
    int base = blockIdx.x * TILE;
    for (int j = 0; j < TILE; j += 256) {
        int i = base + j + t;
        if (i < n) atomicAdd(&cnt[dst[i] >> BSH], 1);
    }
    __syncthreads();
    for (int b = t; b < NBUCK; b += 256) {
        int c = cnt[b];
        lbase[b] = c ? atomicAdd(&bcursor[b], c) : 0;
        cnt[b] = 0;
    }
    __syncthreads();
    for (int j = 0; j < TILE; j += 256) {
        int i = base + j + t;
        if (i < n) {
            int d = dst[i];
            int b = d >> BSH;
            int r = atomicAdd(&cnt[b], 1);
            int2 rec;
            rec.x = src[i] | ((d & (BSPAN - 1)) << 17);
            rec.y = __float_as_int(ew[i]);
            recs[lbase[b] + r] = rec;
        }
    }
}

// ---------------- P3: per-bucket CSR finalize ----------------
__global__ void __launch_bounds__(256) finalize_kernel(
        const int2* __restrict__ recs, const int* __restrict__ bbase,
        int* __restrict__ row_ptr, int2* __restrict__ epack) {
    __shared__ int cnt[BSPAN];
    __shared__ int excl[BSPAN];
    int b = blockIdx.x;
    int t = threadIdx.x;
    int rbase = bbase[b], rend = bbase[b + 1];
    for (int i = t; i < BSPAN; i += 256) cnt[i] = 0;
    __syncthreads();
    for (int k = rbase + t; k < rend; k += 256)
        atomicAdd(&cnt[recs[k].x >> 17], 1);
    __syncthreads();
    if (t < 64) {
        int c[8]; int s = 0;
        #pragma unroll
        for (int k = 0; k < 8; ++k) { c[k] = cnt[t * 8 + k]; s += c[k]; }
        int incl = s;
        #pragma unroll
        for (int off = 1; off < 64; off <<= 1) {
            int u = __shfl_up(incl, off, 64);
            if (t >= off) incl += u;
        }
        int e = incl - s;
        #pragma unroll
        for (int k = 0; k < 8; ++k) { excl[t * 8 + k] = e; e += c[k]; }
    }
    __syncthreads();
    for (int i = t; i < BSPAN; i += 256) {
        int node = b * BSPAN + i;
        if (node < NUM_TEAMS) row_ptr[node] = rbase + excl[i];
        cnt[i] = excl[i];
    }
    __syncthreads();
    for (int k = rbase + t; k < rend; k += 256) {
        int2 rec = recs[k];
        int dloc = rec.x >> 17;
        int r = atomicAdd(&cnt[dloc], 1);
        int2 e; e.x = rec.x & 0x1FFFF; e.y = rec.y;
        epack[rbase + r] = e;
    }
}

// ---------------- f32 -> fp16 convert ----------------
__global__ void __launch_bounds__(256) cvt_kernel(const float* __restrict__ in,
                                                  __half* __restrict__ out, int n2) {
    int i = blockIdx.x * 256 + threadIdx.x;
    if (i < n2) {
        float2 v = *(const float2*)(in + 2 * i);
        *(__half2*)(out + 2 * i) = __floats2half2_rn(v.x, v.y);
    }
}

// ---------------- fused GraphConv (16 lanes/node, half2 lanes) ----------------
// block = 256 threads = 16 nodes x 16 lanes; lane l covers dims {2l, 2l+1}.
// Optional fused epilogue (final layer): uv[node] = [W0h*x3 ; W0a*x3] (8+8 vals).
#define CONV_NPB 16
__global__ void __launch_bounds__(256) conv_kernel(
        const __half* __restrict__ xh,
        const int* __restrict__ row_ptr,
        const int2* __restrict__ epack,
        const float* __restrict__ w_rel,   // [32][32] row-major
        const float* __restrict__ b_rel,   // [32]
        const float* __restrict__ w_root,  // [32][32]
        __half* __restrict__ x_out,        // nullable
        const float* __restrict__ w0,      // [8][64], nullable
        __half* __restrict__ uv_out) {     // [NUM_TEAMS][16], nullable
    __shared__ float s_wrelT[32 * 33];
    __shared__ float s_wrootT[32 * 33];
    __shared__ float s_b[32];
    __shared__ float s_agg[CONV_NPB][34];
    __shared__ float s_x[CONV_NPB][34];
    __shared__ float s_o[CONV_NPB][34];
    __shared__ float s_w0[8 * 66];        // padded stride 66: lane l vs l+8 2-way only

    int t = threadIdx.x;
    for (int i = t; i < 1024; i += 256) {
        int j = i >> 5, d = i & 31;
        s_wrelT[d * 33 + j]  = w_rel[i];
        s_wrootT[d * 33 + j] = w_root[i];
    }
    if (t < 32) s_b[t] = b_rel[t];
    if (w0) {
        for (int i = t; i < 512; i += 256)
            s_w0[(i >> 6) * 66 + (i & 63)] = w0[i];
    }

    int ln = t >> 4;           // node within block
    int l  = t & 15;           // dim-pair index
    int node = blockIdx.x * CONV_NPB + ln;   // 100000 = 6250*16 exact

    const __half2* xh2 = (const __half2*)xh;
    float2 xv = __half22float2(xh2[node * 16 + l]);
    int r0 = row_ptr[node], r1 = row_ptr[node + 1];
    int lim = r1 - 1;

    __half2 acc[8];
    #pragma unroll
    for (int j = 0; j < 8; ++j) acc[j] = __floats2half2_rn(0.f, 0.f);

    for (int k = r0; k < r1; k += 8) {
        int sx[8]; float wv[8];
        #pragma unroll
        for (int j = 0; j < 8; ++j) {
            int idx = k + j;
            idx = idx < lim ? idx : lim;
            long long raw = __builtin_nontemporal_load(
                                (const long long*)(epack + idx));
            sx[j] = (int)(unsigned)(raw & 0xffffffffll);
            wv[j] = __int_as_float((int)(raw >> 32));
        }
        __half2 g[8];
        #pragma unroll
        for (int j = 0; j < 8; ++j) g[j] = xh2[sx[j] * 16 + l];
        #pragma unroll
        for (int j = 0; j < 8; ++j) {
            float w = (k + j <= lim) ? wv[j] : 0.f;
            __half2 w2 = __floats2half2_rn(w, w);
            acc[j] = __hfma2(w2, g[j], acc[j]);
        }
    }
    float2 a = {0.f, 0.f};
    #pragma unroll
    for (int j = 0; j < 8; ++j) {
        float2 f = __half22float2(acc[j]);
        a.x += f.x; a.y += f.y;
    }
    *(float2*)&s_agg[ln][2 * l] = a;
    *(float2*)&s_x[ln][2 * l]   = xv;
    __syncthreads();

    int j0 = 2 * l, j1 = 2 * l + 1;
    float o0 = s_b[j0], o1 = s_b[j1];
    #pragma unroll
    for (int d = 0; d < 32; ++d) {
        float ag = s_agg[ln][d];
        float xx = s_x[ln][d];
        o0 += s_wrelT[d * 33 + j0] * ag + s_wrootT[d * 33 + j0] * xx;
        o1 += s_wrelT[d * 33 + j1] * ag + s_wrootT[d * 33 + j1] * xx;
    }
    o0 = (o0 >= 0.f) ? o0 : 0.01f * o0;
    o1 = (o1 >= 0.f) ? o1 : 0.01f * o1;
    if (x_out)
        ((__half2*)x_out)[node * 16 + l] = __floats2half2_rn(o0, o1);

    if (uv_out) {
        *(float2*)&s_o[ln][2 * l] = make_float2(o0, o1);
        __syncthreads();
        // lane l<8: u_l = sum_d W0[l][d]*x[d]; l>=8: v_{l-8} = sum_d W0[l-8][32+d]*x[d]
        const float* wrow = (l < 8) ? (s_w0 + l * 66) : (s_w0 + (l - 8) * 66 + 32);
        float uvv = 0.f;
        #pragma unroll
        for (int d = 0; d < 32; ++d) uvv += wrow[d] * s_o[ln][d];
        uv_out[node * 16 + l] = __float2half(uvv);
    }
}

// ---------------- final pair MLP (layers 1-4) + log_softmax ----------------
// h1 = lrelu(u[home] + v[away] + b0); uv gathered from 3.2MB L2-resident table.
__global__ void __launch_bounds__(256) mlp_kernel(
        const __half* __restrict__ uv,
        const int* __restrict__ home, const int* __restrict__ away,
        const float* __restrict__ b0,
        const float* __restrict__ w1, const float* __restrict__ b1,
        const float* __restrict__ w2, const float* __restrict__ b2,
        const float* __restrict__ w3, const float* __restrict__ b3,
        const float* __restrict__ w4, const float* __restrict__ b4,
        float* __restrict__ out, int n) {
    __shared__ float s_w1[64], s_w2[64], s_w3[64], s_w4[24];
    __shared__ float s_b0[8], s_b1[8], s_b2[8], s_b3[8], s_b4[3];
    int t = threadIdx.x;
    if (t < 64) { s_w1[t] = w1[t]; s_w2[t] = w2[t]; s_w3[t] = w3[t]; }
    if (t < 24) s_w4[t] = w4[t];
    if (t < 8)  { s_b0[t] = b0[t]; s_b1[t] = b1[t]; s_b2[t] = b2[t]; s_b3[t] = b3[t]; }
    if (t < 3)  s_b4[t] = b4[t];
    __syncthreads();

    int i = blockIdx.x * 256 + t;
    if (i >= n) return;

    int hi = __builtin_nontemporal_load(home + i);
    int ai = __builtin_nontemporal_load(away + i);

    const __half2* pu = (const __half2*)(uv + (size_t)hi * 16);      // u part
    const __half2* pv = (const __half2*)(uv + (size_t)ai * 16 + 8);  // v part

    float h1[8];
    #pragma unroll
    for (int q = 0; q < 4; ++q) {
        float2 fu = __half22float2(pu[q]);
        float2 fv = __half22float2(pv[q]);
        float o0 = fu.x + fv.x + s_b0[2 * q];
        float o1 = fu.y + fv.y + s_b0[2 * q + 1];
        h1[2 * q]     = (o0 >= 0.f) ? o0 : 0.01f * o0;
        h1[2 * q + 1] = (o1 >= 0.f) ? o1 : 0.01f * o1;
    }

    float h2[8];
    #pragma unroll
    for (int j = 0; j < 8; ++j) {
        float o = s_b1[j];
        #pragma unroll
        for (int d = 0; d < 8; ++d) o += s_w1[j * 8 + d] * h1[d];
        h2[j] = (o >= 0.f) ? o : 0.01f * o;
    }
    float h3[8];
    #pragma unroll
    for (int j = 0; j < 8; ++j) {
        float o = s_b2[j];
        #pragma unroll
        for (int d = 0; d < 8; ++d) o += s_w2[j * 8 + d] * h2[d];
        h3[j] = (o >= 0.f) ? o : 0.01f * o;
    }
    float h4[8];
    #pragma unroll
    for (int j = 0; j < 8; ++j) {
        float o = s_b3[j];
        #pragma unroll
        for (int d = 0; d < 8; ++d) o += s_w3[j * 8 + d] * h3[d];
        h4[j] = (o >= 0.f) ? o : 0.01f * o;
    }
    float f[3];
    #pragma unroll
    for (int j = 0; j < 3; ++j) {
        float o = s_b4[j];
        #pragma unroll
        for (int d = 0; d < 8; ++d) o += s_w4[j * 8 + d] * h4[d];
        f[j] = (o >= 0.f) ? o : 0.01f * o;
    }
    float m  = fmaxf(f[0], fmaxf(f[1], f[2]));
    float s  = expf(f[0] - m) + expf(f[1] - m) + expf(f[2] - m);
    float ls = logf(s);
    out[3 * i + 0] = f[0] - m - ls;
    out[3 * i + 1] = f[1] - m - ls;
    out[3 * i + 2] = f[2] - m - ls;
}

// ---------------- launch ----------------

extern "C" void kernel_launch(void* const* d_in, const int* in_sizes, int n_in,
                              void* d_out, int out_size, void* d_ws, size_t ws_size,
                              hipStream_t stream) {
    const int*   edge_index = (const int*)d_in[0];
    const int*   src   = edge_index;
    const int*   dst   = edge_index + N_EDGES;
    const float* ew    = (const float*)d_in[1];
    const int*   home  = (const int*)d_in[2];
    const int*   away  = (const int*)d_in[3];
    const float* embed = (const float*)d_in[4];
    const float* w_rel  = (const float*)d_in[5];
    const float* b_rel  = (const float*)d_in[6];
    const float* w_root = (const float*)d_in[7];
    const float* w0 = (const float*)d_in[8];  const float* b0 = (const float*)d_in[9];
    const float* w1 = (const float*)d_in[10]; const float* b1 = (const float*)d_in[11];
    const float* w2 = (const float*)d_in[12]; const float* b2 = (const float*)d_in[13];
    const float* w3 = (const float*)d_in[14]; const float* b3 = (const float*)d_in[15];
    const float* w4 = (const float*)d_in[16]; const float* b4 = (const float*)d_in[17];
    float* out = (float*)d_out;

    char* ws = (char*)d_ws;
    size_t off = 0;
    auto carve = [&](size_t bytes) -> void* {
        void* p = ws + off;
        off += (bytes + 255) & ~(size_t)255;
        return p;
    };
    int*   row_ptr = (int*)  carve((NUM_TEAMS + 1) * sizeof(int));
    int*   bhist   = (int*)  carve(NBUCK * sizeof(int));
    int*   bbase   = (int*)  carve((NBUCK + 1) * sizeof(int));
    int*   bcursor = (int*)  carve(NBUCK * sizeof(int));
    int2*  recs    = (int2*) carve((size_t)N_EDGES * sizeof(int2));   // dead after P3
    int2*  epack   = (int2*) carve((size_t)N_EDGES * sizeof(int2));
    __half* embedh = (__half*)recs;                           // alias dead recs
    __half* x1h    = (__half*)recs + (size_t)NUM_TEAMS * EMBED;
    __half* x2h    = (__half*)carve((size_t)NUM_TEAMS * EMBED * sizeof(__half));
    __half* uv     = (__half*)carve((size_t)NUM_TEAMS * 16 * sizeof(__half));
    (void)ws_size; (void)in_sizes; (void)n_in; (void)out_size;

    const int conv_blocks = NUM_TEAMS / CONV_NPB;   // 6250 exact
    const int mlp_blocks  = (BQ + 255) / 256;
    const int cvt_pairs   = NUM_TEAMS * EMBED / 2;

    hipMemsetAsync(bhist, 0, NBUCK * sizeof(int), stream);
    bhist_kernel<<<P2_BLOCKS, 256, 0, stream>>>(dst, bhist, N_EDGES);
    bscan_kernel<<<1, 256, 0, stream>>>(bhist, bbase, bcursor, row_ptr);
    partition_kernel<<<P2_BLOCKS, 256, 0, stream>>>(src, dst, ew, bcursor, recs, N_EDGES);
    finalize_kernel<<<NBUCK, 256, 0, stream>>>(recs, bbase, row_ptr, epack);
    cvt_kernel<<<(cvt_pairs + 255) / 256, 256, 0, stream>>>(embed, embedh, cvt_pairs);

    conv_kernel<<<conv_blocks, 256, 0, stream>>>(embedh, row_ptr, epack,
        w_rel + 0 * 1024, b_rel + 0 * 32, w_root + 0 * 1024, x2h, nullptr, nullptr);
    conv_kernel<<<conv_blocks, 256, 0, stream>>>(x2h, row_ptr, epack,
        w_rel + 1 * 1024, b_rel + 1 * 32, w_root + 1 * 1024, x1h, nullptr, nullptr);
    conv_kernel<<<conv_blocks, 256, 0, stream>>>(x1h, row_ptr, epack,
        w_rel + 2 * 1024, b_rel + 2 * 32, w_root + 2 * 1024, nullptr, w0, uv);

    mlp_kernel<<<mlp_blocks, 256, 0, stream>>>(uv, home, away,
        b0, w1, b1, w2, b2, w3, b3, w4, b4, out, BQ);
}